// Round 3
// baseline (304.683 us; speedup 1.0000x reference)
//
#include <hip/hip_runtime.h>
#include <hip/hip_bf16.h>

// LocalSelfAttention: B=4, S=4096, E=1024, WINDOW=256, SCALE=0.125
// Pipeline: cast -> QKV gemm (256^2, BK=64, 8-phase counted-vmcnt schedule)
//           -> V transpose -> windowed attn -> O gemm (+bias+residual)

typedef unsigned short u16;
typedef __attribute__((ext_vector_type(8))) short short8;   // 8 bf16 (4 VGPRs)
typedef __attribute__((ext_vector_type(4))) float f32x4;

__device__ __forceinline__ u16 f2bf(float f) {
    __hip_bfloat16 h = __float2bfloat16(f);
    return __builtin_bit_cast(u16, h);
}

__device__ __forceinline__ void gl_lds16(const u16* g, u16* l) {
    __builtin_amdgcn_global_load_lds(
        (const __attribute__((address_space(1))) void*)g,
        (__attribute__((address_space(3))) void*)l,
        16, 0, 0);
}

// ---------------- cast fp32 -> bf16, vectorized ----------------
__global__ void cast_f32_bf16(const float* __restrict__ src, u16* __restrict__ dst, int n) {
    int i = (blockIdx.x * 256 + threadIdx.x) * 8;
    if (i >= n) return;
    const float4* s = (const float4*)(src + i);
    float4 a = s[0], b = s[1];
    short8 o;
    o[0] = (short)f2bf(a.x); o[1] = (short)f2bf(a.y); o[2] = (short)f2bf(a.z); o[3] = (short)f2bf(a.w);
    o[4] = (short)f2bf(b.x); o[5] = (short)f2bf(b.y); o[6] = (short)f2bf(b.z); o[7] = (short)f2bf(b.w);
    *(short8*)(dst + i) = o;
}

// ---------------- GEMM 256x256 tile, BK=64, 8 waves, 8-phase schedule ----------------
// C[M,N] = A[M,K] @ B[N,K]^T + bias.  A,B bf16 K-major.
// EPI=0: bf16 out, bias by col/1024 from 3 arrays (QKV).  EPI=1: fp32 out + resid.
//
// LDS: buf0.A[0,32K) buf0.B[32K,64K) buf1.A[64K,96K) buf1.B[96K,128K).
// Tile layout: [256 rows][8 slots of 16B], phys slot = kc ^ (row&7); gl_lds dest
// is linear (thread t, load c -> byte c*8192 + t*16); global source pre-swizzled.
//
// Per iter (computes kt=2i from buf0, kt+1 from buf1), 8 phases:
//  P1: rd A0[mf0-3,ks0]+B0[ks0]; stage A(kt+1)->buf1.A; BAR; MFMA; BAR
//  P2: rd A0[mf4-7,ks0];                                BAR; MFMA; BAR
//  P3: rd A0[mf0-3,ks1]+B0[ks1];                        BAR; MFMA; BAR
//  P4: rd A0[mf4-7,ks1]; stage B(kt+2)->buf0.B; vmcnt(4); BAR; MFMA; BAR
//  P5: rd A1[mf0-3,ks0]+B1[ks0]; stage A(kt+2)->buf0.A; BAR; MFMA; BAR
//  P6: rd A1[mf4-7,ks0];                                BAR; MFMA; BAR
//  P7: rd A1[mf0-3,ks1]+B1[ks1];                        BAR; MFMA; BAR
//  P8: rd A1[mf4-7,ks1]; stage B(kt+3)->buf1.B; vmcnt(4); BAR; MFMA; BAR
// Ledger: each staged region's last reads are >=1 phase before the stage issue
// (separated by a barrier + lgkmcnt0); each read is covered by a vmcnt(4)+barrier
// >=3 phases after its stage issue.  Last iter: vmcnt(0) at P4/P8 (stages skipped).
template <int EPI>
__global__ __launch_bounds__(512) void gemm8p(
    const u16* __restrict__ A, const u16* __restrict__ B,
    int M, int N, int K,
    const float* __restrict__ bias0, const float* __restrict__ bias1, const float* __restrict__ bias2,
    u16* __restrict__ Cb, float* __restrict__ Cf, const float* __restrict__ resid)
{
    __shared__ __align__(16) char smbuf[131072];
    char* A0 = smbuf;
    char* B0 = smbuf + 32768;
    char* A1 = smbuf + 65536;
    char* B1 = smbuf + 98304;

    const int t = threadIdx.x;
    const int lane = t & 63, w = t >> 6;
    const int l15 = lane & 15, lk = lane >> 4;
    const int wm = w >> 2, wn = w & 3;

    // XCD-aware chunked swizzle (nwg divisible by 8 for both call sites)
    const int gx = gridDim.x;
    const int nwg = gx * gridDim.y;
    const int bid = blockIdx.y * gx + blockIdx.x;
    const int cpx = nwg >> 3;
    const int swz = (bid & 7) * cpx + (bid >> 3);
    const int m0 = (swz / gx) * 256, n0 = (swz % gx) * 256;

    const int sm_row = t >> 3;                    // 0..63
    const int sm_kc  = (t & 7) ^ (sm_row & 7);    // pre-swizzled k-chunk

    f32x4 acc[8][4];
#pragma unroll
    for (int mf = 0; mf < 8; ++mf)
#pragma unroll
        for (int nf = 0; nf < 4; ++nf)
            acc[mf][nf] = (f32x4){0.f, 0.f, 0.f, 0.f};

    auto STAGE = [&](const u16* G, int gr0, int k0, char* tile) {
#pragma unroll
        for (int c = 0; c < 4; ++c) {
            gl_lds16(G + (size_t)(gr0 + c * 64 + sm_row) * K + k0 + sm_kc * 8,
                     (u16*)(tile + c * 8192 + w * 1024));
        }
    };
    auto RD = [&](const char* tile, int r, int kc) -> short8 {
        return *(const short8*)(tile + r * 128 + ((kc ^ (r & 7)) << 4));
    };

    short8 av[4], bv[4];
    auto LA = [&](const char* tA, int mfb, int ks) {
#pragma unroll
        for (int f = 0; f < 4; ++f)
            av[f] = RD(tA, wm * 128 + (mfb + f) * 16 + l15, ks * 4 + lk);
    };
    auto LB = [&](const char* tB, int ks) {
#pragma unroll
        for (int f = 0; f < 4; ++f)
            bv[f] = RD(tB, wn * 64 + f * 16 + l15, ks * 4 + lk);
    };
    auto MM = [&](int mfb) {
        __builtin_amdgcn_s_setprio(1);
#pragma unroll
        for (int f = 0; f < 4; ++f)
#pragma unroll
            for (int nf = 0; nf < 4; ++nf)
                acc[mfb + f][nf] = __builtin_amdgcn_mfma_f32_16x16x32_bf16(av[f], bv[nf], acc[mfb + f][nf], 0, 0, 0);
        __builtin_amdgcn_s_setprio(0);
    };
    auto BAR1 = [&] {
        __builtin_amdgcn_s_barrier();
        asm volatile("s_waitcnt lgkmcnt(0)" ::: "memory");
        __builtin_amdgcn_sched_barrier(0);
    };
    auto BAR2 = [&] {
        __builtin_amdgcn_s_barrier();
        __builtin_amdgcn_sched_barrier(0);
    };

    const int NT = K >> 6;        // K/64 tiles
    const int NI = NT >> 1;       // 2 tiles per iter

    // prologue: A(0),B(0)->buf0, B(1)->buf1.B; A(1) staged in-loop at P1.
    STAGE(A, m0, 0, A0);
    STAGE(B, n0, 0, B0);
    STAGE(B, n0, 64, B1);
    asm volatile("s_waitcnt vmcnt(4)" ::: "memory");   // A(0),B(0) landed; B(1) in flight
    __builtin_amdgcn_s_barrier();
    __builtin_amdgcn_sched_barrier(0);

    for (int i = 0; i < NI; ++i) {
        const int kt = 2 * i;
        const bool sNext  = (kt + 2 < NT);
        const bool sNext2 = (kt + 3 < NT);

        // P1
        LA(A0, 0, 0); LB(B0, 0);
        STAGE(A, m0, (kt + 1) * 64, A1);
        BAR1(); MM(0); BAR2();
        // P2
        LA(A0, 4, 0);
        BAR1(); MM(4); BAR2();
        // P3
        LA(A0, 0, 1); LB(B0, 1);
        BAR1(); MM(0); BAR2();
        // P4
        LA(A0, 4, 1);
        if (sNext) {
            STAGE(B, n0, (kt + 2) * 64, B0);
            asm volatile("s_waitcnt vmcnt(4)" ::: "memory");
        } else {
            asm volatile("s_waitcnt vmcnt(0)" ::: "memory");
        }
        BAR1(); MM(4); BAR2();
        // P5
        LA(A1, 0, 0); LB(B1, 0);
        if (sNext) STAGE(A, m0, (kt + 2) * 64, A0);
        BAR1(); MM(0); BAR2();
        // P6
        LA(A1, 4, 0);
        BAR1(); MM(4); BAR2();
        // P7
        LA(A1, 0, 1); LB(B1, 1);
        BAR1(); MM(0); BAR2();
        // P8
        LA(A1, 4, 1);
        if (sNext2) {
            STAGE(B, n0, (kt + 3) * 64, B1);
            asm volatile("s_waitcnt vmcnt(4)" ::: "memory");
        } else {
            asm volatile("s_waitcnt vmcnt(0)" ::: "memory");
        }
        BAR1(); MM(4); BAR2();
    }

    // epilogue
#pragma unroll
    for (int mf = 0; mf < 8; ++mf) {
#pragma unroll
        for (int nf = 0; nf < 4; ++nf) {
            int col = n0 + wn * 64 + nf * 16 + l15;
            float bvx;
            if (EPI == 0)
                bvx = (col < 1024) ? bias0[col] : (col < 2048) ? bias1[col - 1024] : bias2[col - 2048];
            else
                bvx = bias0[col];
#pragma unroll
            for (int r = 0; r < 4; ++r) {
                int row = m0 + wm * 128 + mf * 16 + lk * 4 + r;
                float v = acc[mf][nf][r] + bvx;
                if (EPI == 0)
                    Cb[(size_t)row * N + col] = f2bf(v);
                else
                    Cf[(size_t)row * N + col] = v + resid[(size_t)row * N + col];
            }
        }
    }
}

// ---------------- V transpose: per-window V[kk][e] -> Vt[win][e][kk] ----------------
__global__ void transpose_v(const u16* __restrict__ qkv, u16* __restrict__ vt) {
    __shared__ u16 lt[64][72];  // padded
    const int bx = blockIdx.x;
    const int kt = bx & 3, et = (bx >> 2) & 15, win = bx >> 6;
    const int t = threadIdx.x;
#pragma unroll
    for (int p = 0; p < 2; ++p) {
        int e = p * 2048 + t * 8;
        int kr = e >> 6, c = e & 63;
        short8 v = *(const short8*)(qkv + (size_t)(win * 256 + kt * 64 + kr) * 3072 + 2048 + et * 64 + c);
#pragma unroll
        for (int j = 0; j < 8; ++j) lt[c + j][kr] = (u16)v[j];
    }
    __syncthreads();
#pragma unroll
    for (int p = 0; p < 2; ++p) {
        int e = p * 2048 + t * 8;
        int er = e >> 6, kc = e & 63;
        short8 v = *(const short8*)(&lt[er][kc]);
        *(short8*)(vt + (size_t)(win * 1024 + et * 64 + er) * 256 + kt * 64 + kc) = v;
    }
}

// ---------------- windowed causal attention ----------------
__global__ __launch_bounds__(256, 1) void attn_win(
    const u16* __restrict__ qkv, const u16* __restrict__ vt, u16* __restrict__ attn)
{
    __shared__ __align__(16) char smem[100608];
    float* S = (float*)smem;
    u16* P = (u16*)(smem + 65792);
    float* rmax = (float*)(smem + 98560);
    float* rsum = (float*)(smem + 99584);
    u16* Qt = (u16*)smem;
    u16* Kt = (u16*)(smem + 8192);
    u16* Vl = (u16*)smem;

    const int t = threadIdx.x;
    const int lane = t & 63, wv = t >> 6;
    const int l15 = lane & 15, lk = lane >> 4;
    const int bx = blockIdx.x;
    const int win = bx >> 2, qc = bx & 3;
    const size_t qrow0 = (size_t)win * 256 + qc * 64;
    const size_t krow0 = (size_t)win * 256;

    f32x4 acc[4][4];
#pragma unroll
    for (int m = 0; m < 4; ++m)
#pragma unroll
        for (int n = 0; n < 4; ++n)
            acc[m][n] = (f32x4){0.f, 0.f, 0.f, 0.f};

    // ---- phase 1: scores = Q @ K^T over E=1024 ----
    for (int e0 = 0; e0 < 1024; e0 += 64) {
        __syncthreads();
#pragma unroll
        for (int p = 0; p < 2; ++p) {  // Q tile 64x64
            int e = p * 2048 + t * 8;
            int row = e >> 6, col = e & 63;
            short8 v = *(const short8*)(qkv + (qrow0 + row) * 3072 + e0 + col);
            *(short8*)((char*)Qt + row * 128 + ((col * 2) ^ ((row & 7) << 4))) = v;
        }
#pragma unroll
        for (int p = 0; p < 8; ++p) {  // K tile 256x64
            int e = p * 2048 + t * 8;
            int row = e >> 6, col = e & 63;
            short8 v = *(const short8*)(qkv + (krow0 + row) * 3072 + 1024 + e0 + col);
            *(short8*)((char*)Kt + row * 128 + ((col * 2) ^ ((row & 7) << 4))) = v;
        }
        __syncthreads();
#pragma unroll
        for (int ks = 0; ks < 2; ++ks) {
            const int bc = ks * 64 + lk * 16;
            short8 af[4], bfr[4];
#pragma unroll
            for (int m = 0; m < 4; ++m) {
                int row = m * 16 + l15;
                af[m] = *(const short8*)((char*)Qt + row * 128 + (bc ^ ((row & 7) << 4)));
            }
#pragma unroll
            for (int n = 0; n < 4; ++n) {
                int row = wv * 64 + n * 16 + l15;
                bfr[n] = *(const short8*)((char*)Kt + row * 128 + (bc ^ ((row & 7) << 4)));
            }
#pragma unroll
            for (int m = 0; m < 4; ++m)
#pragma unroll
                for (int n = 0; n < 4; ++n)
                    acc[m][n] = __builtin_amdgcn_mfma_f32_16x16x32_bf16(af[m], bfr[n], acc[m][n], 0, 0, 0);
        }
    }
    __syncthreads();

    // ---- phase 2: mask + scale -> S, softmax -> P ----
#pragma unroll
    for (int m = 0; m < 4; ++m) {
#pragma unroll
        for (int n = 0; n < 4; ++n) {
            int col = wv * 64 + n * 16 + l15;
#pragma unroll
            for (int r = 0; r < 4; ++r) {
                int row = m * 16 + lk * 4 + r;
                int qpos = qc * 64 + row;
                float v = acc[m][n][r] * 0.125f;
                S[row * 257 + col] = (col <= qpos) ? v : -1e30f;
            }
        }
    }
    __syncthreads();
    {
        const int row = t & 63, q4 = t >> 6;
        float* Sr = S + row * 257 + q4 * 64;
        float lmax = -1e30f;
        for (int i = 0; i < 64; ++i) lmax = fmaxf(lmax, Sr[i]);
        rmax[row * 4 + q4] = lmax;
        __syncthreads();
        float m4 = fmaxf(fmaxf(rmax[row * 4], rmax[row * 4 + 1]),
                         fmaxf(rmax[row * 4 + 2], rmax[row * 4 + 3]));
        float lsum = 0.f;
        for (int i = 0; i < 64; ++i) {
            float e = __expf(Sr[i] - m4);
            Sr[i] = e;
            lsum += e;
        }
        rsum[row * 4 + q4] = lsum;
        __syncthreads();
        float inv = 1.f / (rsum[row * 4] + rsum[row * 4 + 1] + rsum[row * 4 + 2] + rsum[row * 4 + 3]);
#pragma unroll
        for (int i8 = 0; i8 < 8; ++i8) {
            short8 pv;
#pragma unroll
            for (int j = 0; j < 8; ++j) pv[j] = (short)f2bf(Sr[i8 * 8 + j] * inv);
            int col = q4 * 64 + i8 * 8;
            *(short8*)((char*)P + row * 512 + ((col * 2) ^ ((row & 7) << 4))) = pv;
        }
    }

    // ---- phase 3: out = P @ V via pre-transposed Vt ----
    for (int n0 = 0; n0 < 1024; n0 += 64) {
        __syncthreads();
#pragma unroll
        for (int p = 0; p < 8; ++p) {
            int e = p * 2048 + t * 8;
            int row = e >> 8, col = e & 255;
            short8 v = *(const short8*)(vt + ((size_t)win * 1024 + n0 + row) * 256 + col);
            *(short8*)((char*)Vl + row * 512 + ((col * 2) ^ ((row & 7) << 4))) = v;
        }
        __syncthreads();
        f32x4 acc2[4];
#pragma unroll
        for (int m = 0; m < 4; ++m) acc2[m] = (f32x4){0.f, 0.f, 0.f, 0.f};
#pragma unroll
        for (int ks = 0; ks < 8; ++ks) {
            const int bc = ks * 64 + lk * 16;
            short8 af[4];
#pragma unroll
            for (int m = 0; m < 4; ++m) {
                int row = m * 16 + l15;
                af[m] = *(const short8*)((char*)P + row * 512 + (bc ^ ((row & 7) << 4)));
            }
            int vrow = wv * 16 + l15;
            short8 bfr = *(const short8*)((char*)Vl + vrow * 512 + (bc ^ ((vrow & 7) << 4)));
#pragma unroll
            for (int m = 0; m < 4; ++m)
                acc2[m] = __builtin_amdgcn_mfma_f32_16x16x32_bf16(af[m], bfr, acc2[m], 0, 0, 0);
        }
#pragma unroll
        for (int m = 0; m < 4; ++m) {
#pragma unroll
            for (int r = 0; r < 4; ++r) {
                int row = m * 16 + lk * 4 + r;
                int col = n0 + wv * 16 + l15;
                attn[(qrow0 + row) * 1024 + col] = f2bf(acc2[m][r]);
            }
        }
    }
}

extern "C" void kernel_launch(void* const* d_in, const int* in_sizes, int n_in,
                              void* d_out, int out_size, void* d_ws, size_t ws_size,
                              hipStream_t stream) {
    const float* x  = (const float*)d_in[0];
    const float* Wq = (const float*)d_in[1];
    const float* bq = (const float*)d_in[2];
    const float* Wk = (const float*)d_in[3];
    const float* bk = (const float*)d_in[4];
    const float* Wv = (const float*)d_in[5];
    const float* bv = (const float*)d_in[6];
    const float* Wo = (const float*)d_in[7];
    const float* bo = (const float*)d_in[8];
    float* out = (float*)d_out;

    char* ws = (char*)d_ws;
    u16* xb    = (u16*)(ws);                  // 16384x1024 bf16
    u16* wqkv  = (u16*)(ws + 33554432);       // 3072x1024 bf16
    u16* wo_b  = (u16*)(ws + 39845888);       // 1024x1024 bf16
    u16* qkvb  = (u16*)(ws + 41943040);       // 16384x3072 bf16
    u16* vtb   = (u16*)(ws + 142606336);      // 64x1024x256 bf16
    u16* attnb = (u16*)(ws + 176160768);      // 16384x1024 bf16

    cast_f32_bf16<<<8192, 256, 0, stream>>>(x, xb, 16777216);
    cast_f32_bf16<<<512, 256, 0, stream>>>(Wq, wqkv, 1048576);
    cast_f32_bf16<<<512, 256, 0, stream>>>(Wk, wqkv + 1048576, 1048576);
    cast_f32_bf16<<<512, 256, 0, stream>>>(Wv, wqkv + 2097152, 1048576);
    cast_f32_bf16<<<512, 256, 0, stream>>>(Wo, wo_b, 1048576);

    gemm8p<0><<<dim3(12, 64), 512, 0, stream>>>(xb, wqkv, 16384, 3072, 1024,
                                                bq, bk, bv, qkvb, nullptr, nullptr);
    transpose_v<<<4096, 256, 0, stream>>>(qkvb, vtb);
    attn_win<<<256, 256, 0, stream>>>(qkvb, vtb, attnb);
    gemm8p<1><<<dim3(4, 64), 512, 0, stream>>>(attnb, wo_b, 16384, 1024, 1024,
                                               bo, nullptr, nullptr, nullptr, out, x);
}

// Round 4
// 237.916 us; speedup vs baseline: 1.2806x; 1.2806x over previous
//
#include <hip/hip_runtime.h>
#include <hip/hip_bf16.h>

// LocalSelfAttention: B=4, S=4096, E=1024, WINDOW=256, SCALE=0.125
// Algebraic restructure (no head split => weight products fold):
//   scores_ij = (x G + u)_i . x_j  (+ row-consts that cancel in softmax),
//     G = Wq^T Wk, u = Wk^T bq
//   out = (attn @ x) W2^T + b2 + x,  W2 = Wo Wv, b2 = Wo bv + bo
// Pipeline: cast_x (x->bf16 + x^T) | wcast (WqT,WkT,WvT,Wob) | ub2 (u,b2)
//   | gemm_small_dual (H=G^T, W2) | y = x@H + u | attn (QK^T=y.x, PV=attn@x)
//   | out = z@W2^T + b2 + x

typedef unsigned short u16;
typedef __attribute__((ext_vector_type(8))) short short8;   // 8 bf16 (4 VGPRs)
typedef __attribute__((ext_vector_type(4))) float f32x4;

__device__ __forceinline__ u16 f2bf(float f) {
    __hip_bfloat16 h = __float2bfloat16(f);
    return __builtin_bit_cast(u16, h);
}

// ---------------- cast x -> bf16 (row-major) + bf16 transpose ----------------
// x fp32 [16384,1024] -> xb bf16 [16384,1024], xt bf16 [1024,16384]
// grid dim3(16, 256), 256 threads
__global__ void cast_x(const float* __restrict__ x, u16* __restrict__ xb, u16* __restrict__ xt) {
    __shared__ float lt[64][65];
    const int t = threadIdx.x;
    const int e0 = blockIdx.x * 64, i0 = blockIdx.y * 64;
    const int tr = t >> 3, tc = (t & 7) * 8;
#pragma unroll
    for (int p = 0; p < 2; ++p) {
        int r = p * 32 + tr;
        const float* s = x + (size_t)(i0 + r) * 1024 + e0 + tc;
        float4 a = *(const float4*)s, b = *(const float4*)(s + 4);
        short8 o;
        o[0] = (short)f2bf(a.x); o[1] = (short)f2bf(a.y); o[2] = (short)f2bf(a.z); o[3] = (short)f2bf(a.w);
        o[4] = (short)f2bf(b.x); o[5] = (short)f2bf(b.y); o[6] = (short)f2bf(b.z); o[7] = (short)f2bf(b.w);
        *(short8*)(xb + (size_t)(i0 + r) * 1024 + e0 + tc) = o;
        lt[r][tc + 0] = a.x; lt[r][tc + 1] = a.y; lt[r][tc + 2] = a.z; lt[r][tc + 3] = a.w;
        lt[r][tc + 4] = b.x; lt[r][tc + 5] = b.y; lt[r][tc + 6] = b.z; lt[r][tc + 7] = b.w;
    }
    __syncthreads();
#pragma unroll
    for (int p = 0; p < 2; ++p) {
        int r = p * 32 + tr;   // e index within tile
        short8 o;
#pragma unroll
        for (int j = 0; j < 8; ++j) o[j] = (short)f2bf(lt[tc + j][r]);
        *(short8*)(xt + (size_t)(e0 + r) * 16384 + i0 + tc) = o;
    }
}

// ---------------- weight casts: WqT, WkT, WvT (transposed), Wob (straight) ----------------
// grid 1024 blocks (4 matrices x 256 tiles), 256 threads
__global__ void wcast(const float* __restrict__ Wq, const float* __restrict__ Wk,
                      const float* __restrict__ Wv, const float* __restrict__ Wo,
                      u16* __restrict__ WqT, u16* __restrict__ WkT,
                      u16* __restrict__ WvT, u16* __restrict__ Wob)
{
    __shared__ float lt[64][65];
    const int which = blockIdx.x >> 8;
    const int bid = blockIdx.x & 255;
    const int c0 = (bid & 15) * 64, r0 = (bid >> 4) * 64;
    const int t = threadIdx.x;
    const int tr = t >> 3, tc = (t & 7) * 8;
    const float* src = which == 0 ? Wq : which == 1 ? Wk : which == 2 ? Wv : Wo;
    if (which == 3) {
#pragma unroll
        for (int p = 0; p < 2; ++p) {
            int r = p * 32 + tr;
            const float* s = src + (size_t)(r0 + r) * 1024 + c0 + tc;
            float4 a = *(const float4*)s, b = *(const float4*)(s + 4);
            short8 o;
            o[0] = (short)f2bf(a.x); o[1] = (short)f2bf(a.y); o[2] = (short)f2bf(a.z); o[3] = (short)f2bf(a.w);
            o[4] = (short)f2bf(b.x); o[5] = (short)f2bf(b.y); o[6] = (short)f2bf(b.z); o[7] = (short)f2bf(b.w);
            *(short8*)(Wob + (size_t)(r0 + r) * 1024 + c0 + tc) = o;
        }
        return;
    }
    u16* dst = which == 0 ? WqT : which == 1 ? WkT : WvT;
#pragma unroll
    for (int p = 0; p < 2; ++p) {
        int r = p * 32 + tr;
        const float* s = src + (size_t)(r0 + r) * 1024 + c0 + tc;
        float4 a = *(const float4*)s, b = *(const float4*)(s + 4);
        lt[r][tc + 0] = a.x; lt[r][tc + 1] = a.y; lt[r][tc + 2] = a.z; lt[r][tc + 3] = a.w;
        lt[r][tc + 4] = b.x; lt[r][tc + 5] = b.y; lt[r][tc + 6] = b.z; lt[r][tc + 7] = b.w;
    }
    __syncthreads();
#pragma unroll
    for (int p = 0; p < 2; ++p) {
        int r = p * 32 + tr;
        short8 o;
#pragma unroll
        for (int j = 0; j < 8; ++j) o[j] = (short)f2bf(lt[tc + j][r]);
        *(short8*)(dst + (size_t)(c0 + r) * 1024 + r0 + tc) = o;
    }
}

// ---------------- u = Wk^T bq ; b2 = Wo bv + bo (fp32) ----------------
// grid 68 blocks, 256 threads
__global__ void ub2(const float* __restrict__ Wk, const float* __restrict__ bq,
                    const float* __restrict__ Wo, const float* __restrict__ bv,
                    const float* __restrict__ bo, float* __restrict__ u, float* __restrict__ b2)
{
    const int t = threadIdx.x, bid = blockIdx.x;
    if (bid < 4) {
        int b = bid * 256 + t;
        float acc = 0.f;
        for (int o = 0; o < 1024; ++o) acc += Wk[(size_t)o * 1024 + b] * bq[o];
        u[b] = acc;
    } else {
        int n = (bid - 4) * 16 + (t >> 4);
        int l = t & 15;
        float acc = 0.f;
        for (int m = l; m < 1024; m += 16) acc += Wo[(size_t)n * 1024 + m] * bv[m];
#pragma unroll
        for (int s = 1; s < 16; s <<= 1) acc += __shfl_xor(acc, s, 64);
        if (l == 0) b2[n] = acc + bo[n];
    }
}

// ---------------- dual small GEMM (1024^3): H = WkT @ WqT^T, W2 = Wob @ WvT^T ----------------
// 64x64 tiles, 4 waves, grid 512 (blocks 0-255: H, 256-511: W2)
__global__ __launch_bounds__(256, 4) void gemm_small_dual(
    const u16* __restrict__ HA, const u16* __restrict__ HB, u16* __restrict__ HC,
    const u16* __restrict__ WA, const u16* __restrict__ WB, u16* __restrict__ WC)
{
    __shared__ __align__(16) u16 At[64 * 64], Bt[64 * 64];
    const bool sec = blockIdx.x >= 256;
    const u16* A = sec ? WA : HA;
    const u16* B = sec ? WB : HB;
    u16* C = sec ? WC : HC;
    const int bid = blockIdx.x & 255;
    const int m0 = (bid >> 4) * 64, n0 = (bid & 15) * 64;
    const int t = threadIdx.x, lane = t & 63, w = t >> 6;
    const int l15 = lane & 15, lk = lane >> 4;

    f32x4 acc[4];
#pragma unroll
    for (int m = 0; m < 4; ++m) acc[m] = (f32x4){0.f, 0.f, 0.f, 0.f};

    for (int k0 = 0; k0 < 1024; k0 += 64) {
        __syncthreads();
#pragma unroll
        for (int p = 0; p < 2; ++p) {
            int e = p * 2048 + t * 8;
            int row = e >> 6, col = e & 63;
            short8 va = *(const short8*)(A + (size_t)(m0 + row) * 1024 + k0 + col);
            *(short8*)((char*)At + row * 128 + ((col * 2) ^ ((row & 7) << 4))) = va;
            short8 vb = *(const short8*)(B + (size_t)(n0 + row) * 1024 + k0 + col);
            *(short8*)((char*)Bt + row * 128 + ((col * 2) ^ ((row & 7) << 4))) = vb;
        }
        __syncthreads();
#pragma unroll
        for (int ks = 0; ks < 2; ++ks) {
            int bc = ks * 64 + lk * 16;
            int brow = w * 16 + l15;
            short8 bfr = *(const short8*)((char*)Bt + brow * 128 + (bc ^ ((brow & 7) << 4)));
#pragma unroll
            for (int m = 0; m < 4; ++m) {
                int arow = m * 16 + l15;
                short8 af = *(const short8*)((char*)At + arow * 128 + (bc ^ ((arow & 7) << 4)));
                acc[m] = __builtin_amdgcn_mfma_f32_16x16x32_bf16(af, bfr, acc[m], 0, 0, 0);
            }
        }
    }
#pragma unroll
    for (int m = 0; m < 4; ++m)
#pragma unroll
        for (int r = 0; r < 4; ++r) {
            int row = m0 + m * 16 + lk * 4 + r;
            int col = n0 + w * 16 + l15;
            C[(size_t)row * 1024 + col] = f2bf(acc[m][r]);
        }
}

// ---------------- GEMM: C[M,N] = A[M,K] @ B[N,K]^T + bias (round-1 proven 128^2) ----------------
// EPI=0: bf16 out + bias0. EPI=1: fp32 out = acc + bias0 + resid.
template <int EPI>
__global__ __launch_bounds__(256, 2) void gemm_bt(
    const u16* __restrict__ A, const u16* __restrict__ B,
    int M, int N, int K,
    const float* __restrict__ bias0,
    u16* __restrict__ Cb, float* __restrict__ Cf, const float* __restrict__ resid)
{
    __shared__ __align__(16) u16 At[128 * 64];
    __shared__ __align__(16) u16 Bt[128 * 64];
    const int t = threadIdx.x;
    const int lane = t & 63;
    const int wid = t >> 6;
    const int wm = wid >> 1, wn = wid & 1;
    const int l15 = lane & 15, lk = lane >> 4;
    const int m0 = blockIdx.y * 128, n0 = blockIdx.x * 128;

    f32x4 acc[4][4];
#pragma unroll
    for (int m = 0; m < 4; ++m)
#pragma unroll
        for (int n = 0; n < 4; ++n)
            acc[m][n] = (f32x4){0.f, 0.f, 0.f, 0.f};

    for (int k0 = 0; k0 < K; k0 += 64) {
        __syncthreads();
#pragma unroll
        for (int p = 0; p < 4; ++p) {
            int e = p * 2048 + t * 8;
            int row = e >> 6, col = e & 63;
            short8 va = *(const short8*)(A + (size_t)(m0 + row) * K + k0 + col);
            *(short8*)((char*)At + row * 128 + ((col * 2) ^ ((row & 7) << 4))) = va;
            short8 vb = *(const short8*)(B + (size_t)(n0 + row) * K + k0 + col);
            *(short8*)((char*)Bt + row * 128 + ((col * 2) ^ ((row & 7) << 4))) = vb;
        }
        __syncthreads();
#pragma unroll
        for (int ks = 0; ks < 2; ++ks) {
            const int bc = ks * 64 + lk * 16;
            short8 af[4], bfr[4];
#pragma unroll
            for (int m = 0; m < 4; ++m) {
                int row = wm * 64 + m * 16 + l15;
                af[m] = *(const short8*)((char*)At + row * 128 + (bc ^ ((row & 7) << 4)));
            }
#pragma unroll
            for (int n = 0; n < 4; ++n) {
                int row = wn * 64 + n * 16 + l15;
                bfr[n] = *(const short8*)((char*)Bt + row * 128 + (bc ^ ((row & 7) << 4)));
            }
#pragma unroll
            for (int m = 0; m < 4; ++m)
#pragma unroll
                for (int n = 0; n < 4; ++n)
                    acc[m][n] = __builtin_amdgcn_mfma_f32_16x16x32_bf16(af[m], bfr[n], acc[m][n], 0, 0, 0);
        }
    }

#pragma unroll
    for (int m = 0; m < 4; ++m) {
#pragma unroll
        for (int n = 0; n < 4; ++n) {
            int col = n0 + wn * 64 + n * 16 + l15;
            float bv = bias0[col];
#pragma unroll
            for (int r = 0; r < 4; ++r) {
                int row = m0 + wm * 64 + m * 16 + lk * 4 + r;
                float v = acc[m][n][r] + bv;
                if (EPI == 0)
                    Cb[(size_t)row * N + col] = f2bf(v);
                else
                    Cf[(size_t)row * N + col] = v + resid[(size_t)row * N + col];
            }
        }
    }
}

// ---------------- windowed causal attention ----------------
// One block = (window win, 64 q-rows qc). 4 waves.
// scores = y_w @ x_w^T * SCALE -> causal softmax -> z = attn @ x_w (via xt)
__global__ __launch_bounds__(256, 1) void attn_win(
    const u16* __restrict__ y, const u16* __restrict__ xb,
    const u16* __restrict__ xt, u16* __restrict__ z)
{
    __shared__ __align__(16) char smem[100608];
    float* S = (float*)smem;
    u16* P = (u16*)(smem + 65792);
    float* rmax = (float*)(smem + 98560);
    float* rsum = (float*)(smem + 99584);
    u16* Qt = (u16*)smem;
    u16* Kt = (u16*)(smem + 8192);
    u16* Vl = (u16*)smem;

    const int t = threadIdx.x;
    const int lane = t & 63, wv = t >> 6;
    const int l15 = lane & 15, lk = lane >> 4;
    const int bx = blockIdx.x;
    const int win = bx >> 2, qc = bx & 3;
    const size_t qrow0 = (size_t)win * 256 + qc * 64;
    const size_t krow0 = (size_t)win * 256;

    f32x4 acc[4][4];
#pragma unroll
    for (int m = 0; m < 4; ++m)
#pragma unroll
        for (int n = 0; n < 4; ++n)
            acc[m][n] = (f32x4){0.f, 0.f, 0.f, 0.f};

    // ---- phase 1: scores = y @ x^T over E=1024 ----
    for (int e0 = 0; e0 < 1024; e0 += 64) {
        __syncthreads();
#pragma unroll
        for (int p = 0; p < 2; ++p) {  // Q tile 64x64 from y
            int e = p * 2048 + t * 8;
            int row = e >> 6, col = e & 63;
            short8 v = *(const short8*)(y + (qrow0 + row) * 1024 + e0 + col);
            *(short8*)((char*)Qt + row * 128 + ((col * 2) ^ ((row & 7) << 4))) = v;
        }
#pragma unroll
        for (int p = 0; p < 8; ++p) {  // K tile 256x64 from x
            int e = p * 2048 + t * 8;
            int row = e >> 6, col = e & 63;
            short8 v = *(const short8*)(xb + (krow0 + row) * 1024 + e0 + col);
            *(short8*)((char*)Kt + row * 128 + ((col * 2) ^ ((row & 7) << 4))) = v;
        }
        __syncthreads();
#pragma unroll
        for (int ks = 0; ks < 2; ++ks) {
            const int bc = ks * 64 + lk * 16;
            short8 af[4], bfr[4];
#pragma unroll
            for (int m = 0; m < 4; ++m) {
                int row = m * 16 + l15;
                af[m] = *(const short8*)((char*)Qt + row * 128 + (bc ^ ((row & 7) << 4)));
            }
#pragma unroll
            for (int n = 0; n < 4; ++n) {
                int row = wv * 64 + n * 16 + l15;
                bfr[n] = *(const short8*)((char*)Kt + row * 128 + (bc ^ ((row & 7) << 4)));
            }
#pragma unroll
            for (int m = 0; m < 4; ++m)
#pragma unroll
                for (int n = 0; n < 4; ++n)
                    acc[m][n] = __builtin_amdgcn_mfma_f32_16x16x32_bf16(af[m], bfr[n], acc[m][n], 0, 0, 0);
        }
    }
    __syncthreads();

    // ---- phase 2: mask + scale -> S, softmax -> P ----
#pragma unroll
    for (int m = 0; m < 4; ++m) {
#pragma unroll
        for (int n = 0; n < 4; ++n) {
            int col = wv * 64 + n * 16 + l15;
#pragma unroll
            for (int r = 0; r < 4; ++r) {
                int row = m * 16 + lk * 4 + r;
                int qpos = qc * 64 + row;
                float v = acc[m][n][r] * 0.125f;
                S[row * 257 + col] = (col <= qpos) ? v : -1e30f;
            }
        }
    }
    __syncthreads();
    {
        const int row = t & 63, q4 = t >> 6;
        float* Sr = S + row * 257 + q4 * 64;
        float lmax = -1e30f;
        for (int i = 0; i < 64; ++i) lmax = fmaxf(lmax, Sr[i]);
        rmax[row * 4 + q4] = lmax;
        __syncthreads();
        float m4 = fmaxf(fmaxf(rmax[row * 4], rmax[row * 4 + 1]),
                         fmaxf(rmax[row * 4 + 2], rmax[row * 4 + 3]));
        float lsum = 0.f;
        for (int i = 0; i < 64; ++i) {
            float e = __expf(Sr[i] - m4);
            Sr[i] = e;
            lsum += e;
        }
        rsum[row * 4 + q4] = lsum;
        __syncthreads();
        float inv = 1.f / (rsum[row * 4] + rsum[row * 4 + 1] + rsum[row * 4 + 2] + rsum[row * 4 + 3]);
#pragma unroll
        for (int i8 = 0; i8 < 8; ++i8) {
            short8 pv;
#pragma unroll
            for (int j = 0; j < 8; ++j) pv[j] = (short)f2bf(Sr[i8 * 8 + j] * inv);
            int col = q4 * 64 + i8 * 8;
            *(short8*)((char*)P + row * 512 + ((col * 2) ^ ((row & 7) << 4))) = pv;
        }
    }

    // ---- phase 3: z = attn @ x_w via xt [1024, 16384] ----
    for (int n0 = 0; n0 < 1024; n0 += 64) {
        __syncthreads();
#pragma unroll
        for (int p = 0; p < 8; ++p) {
            int e = p * 2048 + t * 8;
            int row = e >> 8, col = e & 255;
            short8 v = *(const short8*)(xt + (size_t)(n0 + row) * 16384 + win * 256 + col);
            *(short8*)((char*)Vl + row * 512 + ((col * 2) ^ ((row & 7) << 4))) = v;
        }
        __syncthreads();
        f32x4 acc2[4];
#pragma unroll
        for (int m = 0; m < 4; ++m) acc2[m] = (f32x4){0.f, 0.f, 0.f, 0.f};
#pragma unroll
        for (int ks = 0; ks < 8; ++ks) {
            const int bc = ks * 64 + lk * 16;
            short8 af[4];
#pragma unroll
            for (int m = 0; m < 4; ++m) {
                int row = m * 16 + l15;
                af[m] = *(const short8*)((char*)P + row * 512 + (bc ^ ((row & 7) << 4)));
            }
            int vrow = wv * 16 + l15;
            short8 bfr = *(const short8*)((char*)Vl + vrow * 512 + (bc ^ ((vrow & 7) << 4)));
#pragma unroll
            for (int m = 0; m < 4; ++m)
                acc2[m] = __builtin_amdgcn_mfma_f32_16x16x32_bf16(af[m], bfr, acc2[m], 0, 0, 0);
        }
#pragma unroll
        for (int m = 0; m < 4; ++m) {
#pragma unroll
            for (int r = 0; r < 4; ++r) {
                int row = m * 16 + lk * 4 + r;
                int col = n0 + wv * 16 + l15;
                z[(qrow0 + row) * 1024 + col] = f2bf(acc2[m][r]);
            }
        }
    }
}

extern "C" void kernel_launch(void* const* d_in, const int* in_sizes, int n_in,
                              void* d_out, int out_size, void* d_ws, size_t ws_size,
                              hipStream_t stream) {
    const float* x  = (const float*)d_in[0];
    const float* Wq = (const float*)d_in[1];
    const float* bq = (const float*)d_in[2];
    const float* Wk = (const float*)d_in[3];
    // bk (d_in[4]) contributes only row-constants to scores -> cancels in softmax
    const float* Wv = (const float*)d_in[5];
    const float* bv = (const float*)d_in[6];
    const float* Wo = (const float*)d_in[7];
    const float* bo = (const float*)d_in[8];
    float* out = (float*)d_out;

    char* ws = (char*)d_ws;
    u16* xb  = (u16*)(ws);                    // [16384,1024] bf16
    u16* xt  = (u16*)(ws + 33554432);         // [1024,16384] bf16
    u16* yb  = (u16*)(ws + 67108864);         // [16384,1024] bf16
    u16* zb  = (u16*)(ws + 100663296);        // [16384,1024] bf16
    u16* WqT = (u16*)(ws + 134217728);        // [1024,1024] bf16 (= Wq^T)
    u16* WkT = (u16*)(ws + 136314880);        // [1024,1024] bf16 (= Wk^T)
    u16* WvT = (u16*)(ws + 138412032);        // [1024,1024] bf16 (= Wv^T)
    u16* Wob = (u16*)(ws + 140509184);        // [1024,1024] bf16 (= Wo)
    u16* Hb  = (u16*)(ws + 142606336);        // [1024,1024] bf16 H = G^T = Wk^T Wq
    u16* W2b = (u16*)(ws + 144703488);        // [1024,1024] bf16 W2 = Wo Wv
    float* u_  = (float*)(ws + 146800640);    // [1024] fp32
    float* b2_ = (float*)(ws + 146804736);    // [1024] fp32

    cast_x<<<dim3(16, 256), 256, 0, stream>>>(x, xb, xt);
    wcast<<<1024, 256, 0, stream>>>(Wq, Wk, Wv, Wo, WqT, WkT, WvT, Wob);
    ub2<<<68, 256, 0, stream>>>(Wk, bq, Wo, bv, bo, u_, b2_);
    // H[b,a] = sum_o Wk[o,b] Wq[o,a]  (used as B-operand of y-gemm)
    // W2[n,k] = sum_m Wo[n,m] Wv[m,k] (used as B-operand of out-gemm)
    gemm_small_dual<<<512, 256, 0, stream>>>(WkT, WqT, Hb, Wob, WvT, W2b);
    // y = x @ H^T(B-layout) + u
    gemm_bt<0><<<dim3(8, 128), 256, 0, stream>>>(xb, Hb, 16384, 1024, 1024, u_, yb, nullptr, nullptr);
    attn_win<<<256, 256, 0, stream>>>(yb, xb, xt, zb);
    // out = z @ W2^T + b2 + x
    gemm_bt<1><<<dim3(8, 128), 256, 0, stream>>>(zb, W2b, 16384, 1024, 1024, b2_, nullptr, out, x);
}

// Round 5
// 221.208 us; speedup vs baseline: 1.3774x; 1.0755x over previous
//
#include <hip/hip_runtime.h>
#include <hip/hip_bf16.h>

// LocalSelfAttention: B=4, S=4096, E=1024, WINDOW=256, SCALE=0.125
// Algebraic restructure (no head split => weight products fold):
//   scores_ij = (x G + u)_i . x_j  (+ row-consts that cancel in softmax),
//     G = Wq^T Wk, u = Wk^T bq
//   out = (attn @ x) W2^T + b2 + x,  W2 = Wo Wv, b2 = Wo bv + bo
// Round 5: XCD-chunked block swizzle on gemm_bt + attn_win (A-tile / K-window
// sharing blocks colocate on one XCD's L2).

typedef unsigned short u16;
typedef __attribute__((ext_vector_type(8))) short short8;   // 8 bf16 (4 VGPRs)
typedef __attribute__((ext_vector_type(4))) float f32x4;

__device__ __forceinline__ u16 f2bf(float f) {
    __hip_bfloat16 h = __float2bfloat16(f);
    return __builtin_bit_cast(u16, h);
}

// ---------------- cast x -> bf16 (row-major) + bf16 transpose ----------------
__global__ void cast_x(const float* __restrict__ x, u16* __restrict__ xb, u16* __restrict__ xt) {
    __shared__ float lt[64][65];
    const int t = threadIdx.x;
    const int e0 = blockIdx.x * 64, i0 = blockIdx.y * 64;
    const int tr = t >> 3, tc = (t & 7) * 8;
#pragma unroll
    for (int p = 0; p < 2; ++p) {
        int r = p * 32 + tr;
        const float* s = x + (size_t)(i0 + r) * 1024 + e0 + tc;
        float4 a = *(const float4*)s, b = *(const float4*)(s + 4);
        short8 o;
        o[0] = (short)f2bf(a.x); o[1] = (short)f2bf(a.y); o[2] = (short)f2bf(a.z); o[3] = (short)f2bf(a.w);
        o[4] = (short)f2bf(b.x); o[5] = (short)f2bf(b.y); o[6] = (short)f2bf(b.z); o[7] = (short)f2bf(b.w);
        *(short8*)(xb + (size_t)(i0 + r) * 1024 + e0 + tc) = o;
        lt[r][tc + 0] = a.x; lt[r][tc + 1] = a.y; lt[r][tc + 2] = a.z; lt[r][tc + 3] = a.w;
        lt[r][tc + 4] = b.x; lt[r][tc + 5] = b.y; lt[r][tc + 6] = b.z; lt[r][tc + 7] = b.w;
    }
    __syncthreads();
#pragma unroll
    for (int p = 0; p < 2; ++p) {
        int r = p * 32 + tr;   // e index within tile
        short8 o;
#pragma unroll
        for (int j = 0; j < 8; ++j) o[j] = (short)f2bf(lt[tc + j][r]);
        *(short8*)(xt + (size_t)(e0 + r) * 16384 + i0 + tc) = o;
    }
}

// ---------------- weight casts: WqT, WkT, WvT (transposed), Wob (straight) ----------------
__global__ void wcast(const float* __restrict__ Wq, const float* __restrict__ Wk,
                      const float* __restrict__ Wv, const float* __restrict__ Wo,
                      u16* __restrict__ WqT, u16* __restrict__ WkT,
                      u16* __restrict__ WvT, u16* __restrict__ Wob)
{
    __shared__ float lt[64][65];
    const int which = blockIdx.x >> 8;
    const int bid = blockIdx.x & 255;
    const int c0 = (bid & 15) * 64, r0 = (bid >> 4) * 64;
    const int t = threadIdx.x;
    const int tr = t >> 3, tc = (t & 7) * 8;
    const float* src = which == 0 ? Wq : which == 1 ? Wk : which == 2 ? Wv : Wo;
    if (which == 3) {
#pragma unroll
        for (int p = 0; p < 2; ++p) {
            int r = p * 32 + tr;
            const float* s = src + (size_t)(r0 + r) * 1024 + c0 + tc;
            float4 a = *(const float4*)s, b = *(const float4*)(s + 4);
            short8 o;
            o[0] = (short)f2bf(a.x); o[1] = (short)f2bf(a.y); o[2] = (short)f2bf(a.z); o[3] = (short)f2bf(a.w);
            o[4] = (short)f2bf(b.x); o[5] = (short)f2bf(b.y); o[6] = (short)f2bf(b.z); o[7] = (short)f2bf(b.w);
            *(short8*)(Wob + (size_t)(r0 + r) * 1024 + c0 + tc) = o;
        }
        return;
    }
    u16* dst = which == 0 ? WqT : which == 1 ? WkT : WvT;
#pragma unroll
    for (int p = 0; p < 2; ++p) {
        int r = p * 32 + tr;
        const float* s = src + (size_t)(r0 + r) * 1024 + c0 + tc;
        float4 a = *(const float4*)s, b = *(const float4*)(s + 4);
        lt[r][tc + 0] = a.x; lt[r][tc + 1] = a.y; lt[r][tc + 2] = a.z; lt[r][tc + 3] = a.w;
        lt[r][tc + 4] = b.x; lt[r][tc + 5] = b.y; lt[r][tc + 6] = b.z; lt[r][tc + 7] = b.w;
    }
    __syncthreads();
#pragma unroll
    for (int p = 0; p < 2; ++p) {
        int r = p * 32 + tr;
        short8 o;
#pragma unroll
        for (int j = 0; j < 8; ++j) o[j] = (short)f2bf(lt[tc + j][r]);
        *(short8*)(dst + (size_t)(c0 + r) * 1024 + r0 + tc) = o;
    }
}

// ---------------- u = Wk^T bq ; b2 = Wo bv + bo (fp32) ----------------
__global__ void ub2(const float* __restrict__ Wk, const float* __restrict__ bq,
                    const float* __restrict__ Wo, const float* __restrict__ bv,
                    const float* __restrict__ bo, float* __restrict__ u, float* __restrict__ b2)
{
    const int t = threadIdx.x, bid = blockIdx.x;
    if (bid < 4) {
        int b = bid * 256 + t;
        float acc = 0.f;
        for (int o = 0; o < 1024; ++o) acc += Wk[(size_t)o * 1024 + b] * bq[o];
        u[b] = acc;
    } else {
        int n = (bid - 4) * 16 + (t >> 4);
        int l = t & 15;
        float acc = 0.f;
        for (int m = l; m < 1024; m += 16) acc += Wo[(size_t)n * 1024 + m] * bv[m];
#pragma unroll
        for (int s = 1; s < 16; s <<= 1) acc += __shfl_xor(acc, s, 64);
        if (l == 0) b2[n] = acc + bo[n];
    }
}

// ---------------- dual small GEMM (1024^3): H = WkT @ WqT^T, W2 = Wob @ WvT^T ----------------
__global__ __launch_bounds__(256, 4) void gemm_small_dual(
    const u16* __restrict__ HA, const u16* __restrict__ HB, u16* __restrict__ HC,
    const u16* __restrict__ WA, const u16* __restrict__ WB, u16* __restrict__ WC)
{
    __shared__ __align__(16) u16 At[64 * 64], Bt[64 * 64];
    const bool sec = blockIdx.x >= 256;
    const u16* A = sec ? WA : HA;
    const u16* B = sec ? WB : HB;
    u16* C = sec ? WC : HC;
    const int bid = blockIdx.x & 255;
    const int m0 = (bid >> 4) * 64, n0 = (bid & 15) * 64;
    const int t = threadIdx.x, lane = t & 63, w = t >> 6;
    const int l15 = lane & 15, lk = lane >> 4;

    f32x4 acc[4];
#pragma unroll
    for (int m = 0; m < 4; ++m) acc[m] = (f32x4){0.f, 0.f, 0.f, 0.f};

    for (int k0 = 0; k0 < 1024; k0 += 64) {
        __syncthreads();
#pragma unroll
        for (int p = 0; p < 2; ++p) {
            int e = p * 2048 + t * 8;
            int row = e >> 6, col = e & 63;
            short8 va = *(const short8*)(A + (size_t)(m0 + row) * 1024 + k0 + col);
            *(short8*)((char*)At + row * 128 + ((col * 2) ^ ((row & 7) << 4))) = va;
            short8 vb = *(const short8*)(B + (size_t)(n0 + row) * 1024 + k0 + col);
            *(short8*)((char*)Bt + row * 128 + ((col * 2) ^ ((row & 7) << 4))) = vb;
        }
        __syncthreads();
#pragma unroll
        for (int ks = 0; ks < 2; ++ks) {
            int bc = ks * 64 + lk * 16;
            int brow = w * 16 + l15;
            short8 bfr = *(const short8*)((char*)Bt + brow * 128 + (bc ^ ((brow & 7) << 4)));
#pragma unroll
            for (int m = 0; m < 4; ++m) {
                int arow = m * 16 + l15;
                short8 af = *(const short8*)((char*)At + arow * 128 + (bc ^ ((arow & 7) << 4)));
                acc[m] = __builtin_amdgcn_mfma_f32_16x16x32_bf16(af, bfr, acc[m], 0, 0, 0);
            }
        }
    }
#pragma unroll
    for (int m = 0; m < 4; ++m)
#pragma unroll
        for (int r = 0; r < 4; ++r) {
            int row = m0 + m * 16 + lk * 4 + r;
            int col = n0 + w * 16 + l15;
            C[(size_t)row * 1024 + col] = f2bf(acc[m][r]);
        }
}

// ---------------- GEMM: C[M,N] = A[M,K] @ B[N,K]^T + bias (128^2, XCD-swizzled) ----------------
// Grid must be dim3(8, M/128); nwg divisible by 8.
// EPI=0: bf16 out + bias0. EPI=1: fp32 out = acc + bias0 + resid.
template <int EPI>
__global__ __launch_bounds__(256, 2) void gemm_bt(
    const u16* __restrict__ A, const u16* __restrict__ B,
    int M, int N, int K,
    const float* __restrict__ bias0,
    u16* __restrict__ Cb, float* __restrict__ Cf, const float* __restrict__ resid)
{
    __shared__ __align__(16) u16 At[128 * 64];
    __shared__ __align__(16) u16 Bt[128 * 64];
    const int t = threadIdx.x;
    const int lane = t & 63;
    const int wid = t >> 6;
    const int wm = wid >> 1, wn = wid & 1;
    const int l15 = lane & 15, lk = lane >> 4;

    // XCD-chunked swizzle: blocks sharing an A row-tile (same tm) colocate per XCD.
    const int bid = blockIdx.y * gridDim.x + blockIdx.x;
    const int nwg = gridDim.x * gridDim.y;
    const int cpx = nwg >> 3;
    const int swz = (bid & 7) * cpx + (bid >> 3);
    const int tn = swz & 7;          // gridDim.x == 8
    const int tm = swz >> 3;
    const int m0 = tm * 128, n0 = tn * 128;

    f32x4 acc[4][4];
#pragma unroll
    for (int m = 0; m < 4; ++m)
#pragma unroll
        for (int n = 0; n < 4; ++n)
            acc[m][n] = (f32x4){0.f, 0.f, 0.f, 0.f};

    for (int k0 = 0; k0 < K; k0 += 64) {
        __syncthreads();
#pragma unroll
        for (int p = 0; p < 4; ++p) {
            int e = p * 2048 + t * 8;
            int row = e >> 6, col = e & 63;
            short8 va = *(const short8*)(A + (size_t)(m0 + row) * K + k0 + col);
            *(short8*)((char*)At + row * 128 + ((col * 2) ^ ((row & 7) << 4))) = va;
            short8 vb = *(const short8*)(B + (size_t)(n0 + row) * K + k0 + col);
            *(short8*)((char*)Bt + row * 128 + ((col * 2) ^ ((row & 7) << 4))) = vb;
        }
        __syncthreads();
#pragma unroll
        for (int ks = 0; ks < 2; ++ks) {
            const int bc = ks * 64 + lk * 16;
            short8 af[4], bfr[4];
#pragma unroll
            for (int m = 0; m < 4; ++m) {
                int row = wm * 64 + m * 16 + l15;
                af[m] = *(const short8*)((char*)At + row * 128 + (bc ^ ((row & 7) << 4)));
            }
#pragma unroll
            for (int n = 0; n < 4; ++n) {
                int row = wn * 64 + n * 16 + l15;
                bfr[n] = *(const short8*)((char*)Bt + row * 128 + (bc ^ ((row & 7) << 4)));
            }
#pragma unroll
            for (int m = 0; m < 4; ++m)
#pragma unroll
                for (int n = 0; n < 4; ++n)
                    acc[m][n] = __builtin_amdgcn_mfma_f32_16x16x32_bf16(af[m], bfr[n], acc[m][n], 0, 0, 0);
        }
    }

#pragma unroll
    for (int m = 0; m < 4; ++m) {
#pragma unroll
        for (int n = 0; n < 4; ++n) {
            int col = n0 + wn * 64 + n * 16 + l15;
            float bv = bias0[col];
#pragma unroll
            for (int r = 0; r < 4; ++r) {
                int row = m0 + wm * 64 + m * 16 + lk * 4 + r;
                float v = acc[m][n][r] + bv;
                if (EPI == 0)
                    Cb[(size_t)row * N + col] = f2bf(v);
                else
                    Cf[(size_t)row * N + col] = v + resid[(size_t)row * N + col];
            }
        }
    }
}

// ---------------- windowed causal attention (XCD-swizzled) ----------------
// One block = (window win, 64 q-rows qc). 4 waves.  Grid 256.
__global__ __launch_bounds__(256, 1) void attn_win(
    const u16* __restrict__ y, const u16* __restrict__ xb,
    const u16* __restrict__ xt, u16* __restrict__ z)
{
    __shared__ __align__(16) char smem[100608];
    float* S = (float*)smem;
    u16* P = (u16*)(smem + 65792);
    float* rmax = (float*)(smem + 98560);
    float* rsum = (float*)(smem + 99584);
    u16* Qt = (u16*)smem;
    u16* Kt = (u16*)(smem + 8192);
    u16* Vl = (u16*)smem;

    const int t = threadIdx.x;
    const int lane = t & 63, wv = t >> 6;
    const int l15 = lane & 15, lk = lane >> 4;
    // XCD swizzle: the 4 q-chunk blocks of each window colocate per XCD.
    const int bid = blockIdx.x;
    const int swz = (bid & 7) * 32 + (bid >> 3);
    const int win = swz >> 2, qc = swz & 3;
    const size_t qrow0 = (size_t)win * 256 + qc * 64;
    const size_t krow0 = (size_t)win * 256;

    f32x4 acc[4][4];
#pragma unroll
    for (int m = 0; m < 4; ++m)
#pragma unroll
        for (int n = 0; n < 4; ++n)
            acc[m][n] = (f32x4){0.f, 0.f, 0.f, 0.f};

    // ---- phase 1: scores = y @ x^T over E=1024 ----
    for (int e0 = 0; e0 < 1024; e0 += 64) {
        __syncthreads();
#pragma unroll
        for (int p = 0; p < 2; ++p) {  // Q tile 64x64 from y
            int e = p * 2048 + t * 8;
            int row = e >> 6, col = e & 63;
            short8 v = *(const short8*)(y + (qrow0 + row) * 1024 + e0 + col);
            *(short8*)((char*)Qt + row * 128 + ((col * 2) ^ ((row & 7) << 4))) = v;
        }
#pragma unroll
        for (int p = 0; p < 8; ++p) {  // K tile 256x64 from x
            int e = p * 2048 + t * 8;
            int row = e >> 6, col = e & 63;
            short8 v = *(const short8*)(xb + (krow0 + row) * 1024 + e0 + col);
            *(short8*)((char*)Kt + row * 128 + ((col * 2) ^ ((row & 7) << 4))) = v;
        }
        __syncthreads();
#pragma unroll
        for (int ks = 0; ks < 2; ++ks) {
            const int bc = ks * 64 + lk * 16;
            short8 af[4], bfr[4];
#pragma unroll
            for (int m = 0; m < 4; ++m) {
                int row = m * 16 + l15;
                af[m] = *(const short8*)((char*)Qt + row * 128 + (bc ^ ((row & 7) << 4)));
            }
#pragma unroll
            for (int n = 0; n < 4; ++n) {
                int row = wv * 64 + n * 16 + l15;
                bfr[n] = *(const short8*)((char*)Kt + row * 128 + (bc ^ ((row & 7) << 4)));
            }
#pragma unroll
            for (int m = 0; m < 4; ++m)
#pragma unroll
                for (int n = 0; n < 4; ++n)
                    acc[m][n] = __builtin_amdgcn_mfma_f32_16x16x32_bf16(af[m], bfr[n], acc[m][n], 0, 0, 0);
        }
    }
    __syncthreads();

    // ---- phase 2: mask + scale -> S, softmax -> P ----
#pragma unroll
    for (int m = 0; m < 4; ++m) {
#pragma unroll
        for (int n = 0; n < 4; ++n) {
            int col = wv * 64 + n * 16 + l15;
#pragma unroll
            for (int r = 0; r < 4; ++r) {
                int row = m * 16 + lk * 4 + r;
                int qpos = qc * 64 + row;
                float v = acc[m][n][r] * 0.125f;
                S[row * 257 + col] = (col <= qpos) ? v : -1e30f;
            }
        }
    }
    __syncthreads();
    {
        const int row = t & 63, q4 = t >> 6;
        float* Sr = S + row * 257 + q4 * 64;
        float lmax = -1e30f;
        for (int i = 0; i < 64; ++i) lmax = fmaxf(lmax, Sr[i]);
        rmax[row * 4 + q4] = lmax;
        __syncthreads();
        float m4 = fmaxf(fmaxf(rmax[row * 4], rmax[row * 4 + 1]),
                         fmaxf(rmax[row * 4 + 2], rmax[row * 4 + 3]));
        float lsum = 0.f;
        for (int i = 0; i < 64; ++i) {
            float e = __expf(Sr[i] - m4);
            Sr[i] = e;
            lsum += e;
        }
        rsum[row * 4 + q4] = lsum;
        __syncthreads();
        float inv = 1.f / (rsum[row * 4] + rsum[row * 4 + 1] + rsum[row * 4 + 2] + rsum[row * 4 + 3]);
#pragma unroll
        for (int i8 = 0; i8 < 8; ++i8) {
            short8 pv;
#pragma unroll
            for (int j = 0; j < 8; ++j) pv[j] = (short)f2bf(Sr[i8 * 8 + j] * inv);
            int col = q4 * 64 + i8 * 8;
            *(short8*)((char*)P + row * 512 + ((col * 2) ^ ((row & 7) << 4))) = pv;
        }
    }

    // ---- phase 3: z = attn @ x_w via xt [1024, 16384] ----
    for (int n0 = 0; n0 < 1024; n0 += 64) {
        __syncthreads();
#pragma unroll
        for (int p = 0; p < 8; ++p) {
            int e = p * 2048 + t * 8;
            int row = e >> 8, col = e & 255;
            short8 v = *(const short8*)(xt + (size_t)(n0 + row) * 16384 + win * 256 + col);
            *(short8*)((char*)Vl + row * 512 + ((col * 2) ^ ((row & 7) << 4))) = v;
        }
        __syncthreads();
        f32x4 acc2[4];
#pragma unroll
        for (int m = 0; m < 4; ++m) acc2[m] = (f32x4){0.f, 0.f, 0.f, 0.f};
#pragma unroll
        for (int ks = 0; ks < 8; ++ks) {
            const int bc = ks * 64 + lk * 16;
            short8 af[4];
#pragma unroll
            for (int m = 0; m < 4; ++m) {
                int row = m * 16 + l15;
                af[m] = *(const short8*)((char*)P + row * 512 + (bc ^ ((row & 7) << 4)));
            }
            int vrow = wv * 16 + l15;
            short8 bfr = *(const short8*)((char*)Vl + vrow * 512 + (bc ^ ((vrow & 7) << 4)));
#pragma unroll
            for (int m = 0; m < 4; ++m)
                acc2[m] = __builtin_amdgcn_mfma_f32_16x16x32_bf16(af[m], bfr, acc2[m], 0, 0, 0);
        }
#pragma unroll
        for (int m = 0; m < 4; ++m) {
#pragma unroll
            for (int r = 0; r < 4; ++r) {
                int row = m * 16 + lk * 4 + r;
                int col = n0 + wv * 16 + l15;
                z[(qrow0 + row) * 1024 + col] = f2bf(acc2[m][r]);
            }
        }
    }
}

extern "C" void kernel_launch(void* const* d_in, const int* in_sizes, int n_in,
                              void* d_out, int out_size, void* d_ws, size_t ws_size,
                              hipStream_t stream) {
    const float* x  = (const float*)d_in[0];
    const float* Wq = (const float*)d_in[1];
    const float* bq = (const float*)d_in[2];
    const float* Wk = (const float*)d_in[3];
    // bk (d_in[4]) contributes only row-constants to scores -> cancels in softmax
    const float* Wv = (const float*)d_in[5];
    const float* bv = (const float*)d_in[6];
    const float* Wo = (const float*)d_in[7];
    const float* bo = (const float*)d_in[8];
    float* out = (float*)d_out;

    char* ws = (char*)d_ws;
    u16* xb  = (u16*)(ws);                    // [16384,1024] bf16
    u16* xt  = (u16*)(ws + 33554432);         // [1024,16384] bf16
    u16* yb  = (u16*)(ws + 67108864);         // [16384,1024] bf16
    u16* zb  = (u16*)(ws + 100663296);        // [16384,1024] bf16
    u16* WqT = (u16*)(ws + 134217728);        // [1024,1024] bf16 (= Wq^T)
    u16* WkT = (u16*)(ws + 136314880);        // [1024,1024] bf16 (= Wk^T)
    u16* WvT = (u16*)(ws + 138412032);        // [1024,1024] bf16 (= Wv^T)
    u16* Wob = (u16*)(ws + 140509184);        // [1024,1024] bf16 (= Wo)
    u16* Hb  = (u16*)(ws + 142606336);        // [1024,1024] bf16 H = G^T = Wk^T Wq
    u16* W2b = (u16*)(ws + 144703488);        // [1024,1024] bf16 W2 = Wo Wv
    float* u_  = (float*)(ws + 146800640);    // [1024] fp32
    float* b2_ = (float*)(ws + 146804736);    // [1024] fp32

    cast_x<<<dim3(16, 256), 256, 0, stream>>>(x, xb, xt);
    wcast<<<1024, 256, 0, stream>>>(Wq, Wk, Wv, Wo, WqT, WkT, WvT, Wob);
    ub2<<<68, 256, 0, stream>>>(Wk, bq, Wo, bv, bo, u_, b2_);
    gemm_small_dual<<<512, 256, 0, stream>>>(WkT, WqT, Hb, Wob, WvT, W2b);
    // y = x @ H^T(B-layout) + u
    gemm_bt<0><<<dim3(8, 128), 256, 0, stream>>>(xb, Hb, 16384, 1024, 1024, u_, yb, nullptr, nullptr);
    attn_win<<<256, 256, 0, stream>>>(yb, xb, xt, zb);
    // out = z @ W2^T + b2 + x
    gemm_bt<1><<<dim3(8, 128), 256, 0, stream>>>(zb, W2b, 16384, 1024, 1024, b2_, nullptr, out, x);
}